// Round 4
// baseline (443.792 us; speedup 1.0000x reference)
//
#include <hip/hip_runtime.h>
#include <cstddef>

// Problem constants: B=4, S=2048, D=1024, H=16, HD=64
constexpr int Bn  = 4;
constexpr int Sn  = 2048;
constexpr int Dn  = 1024;
constexpr int Hn  = 16;
constexpr int HDn = 64;

typedef __bf16 bf16;
typedef __attribute__((ext_vector_type(8))) __bf16 bf16x8;
typedef __attribute__((ext_vector_type(4))) __bf16 bf16x4;
typedef __attribute__((ext_vector_type(4))) float  f32x4;

typedef __attribute__((address_space(1))) const void gvoid;
typedef __attribute__((address_space(3))) void lvoid;

// ---------------------------------------------------------------------------
// Elementwise fp32 -> bf16 (x staging)
// ---------------------------------------------------------------------------
__global__ __launch_bounds__(256) void conv_f32_bf16_k(
    const float* __restrict__ in, bf16* __restrict__ out, int n)
{
    int i = (blockIdx.x * 256 + threadIdx.x) * 4;
    if (i + 3 < n) {
        float4 v = *(const float4*)(in + i);
        bf16 o[4] = {(bf16)v.x, (bf16)v.y, (bf16)v.z, (bf16)v.w};
        *(ulong1*)(out + i) = *(ulong1*)o;  // 8B store
    }
}

// ---------------------------------------------------------------------------
// Weight transpose + convert: W[k][n] fp32 -> Wt[n][k] bf16. 64x64 tiles.
// ---------------------------------------------------------------------------
__global__ __launch_bounds__(256) void conv_wt_k(
    const float* __restrict__ w0, const float* __restrict__ w1,
    const float* __restrict__ w2, const float* __restrict__ w3,
    bf16* __restrict__ o0, bf16* __restrict__ o1,
    bf16* __restrict__ o2, bf16* __restrict__ o3)
{
    const float* W = (blockIdx.z == 0) ? w0 : (blockIdx.z == 1) ? w1
                   : (blockIdx.z == 2) ? w2 : w3;
    bf16* O = (blockIdx.z == 0) ? o0 : (blockIdx.z == 1) ? o1
            : (blockIdx.z == 2) ? o2 : o3;
    __shared__ float t[64][65];
    const int tid = threadIdx.x;
    const int k0 = blockIdx.x * 64;   // row of W (k-dim)
    const int n0 = blockIdx.y * 64;   // col of W (n-dim)
    #pragma unroll
    for (int p = 0; p < 16; ++p) {
        const int idx = p * 256 + tid;
        const int r = idx >> 6, c = idx & 63;
        t[r][c] = W[(size_t)(k0 + r) * Dn + n0 + c];
    }
    __syncthreads();
    #pragma unroll
    for (int p = 0; p < 16; ++p) {
        const int idx = p * 256 + tid;
        const int r = idx >> 6, c = idx & 63;   // r: n-offset, c: k-offset
        O[(size_t)(n0 + r) * Dn + k0 + c] = (bf16)t[c][r];
    }
}

// ---------------------------------------------------------------------------
// bf16 MFMA GEMM, m97 structure: out = (A(8192x1024) @ Bt^T + bias) * scale,
// Bt is [N][K] bf16. 128x128 tile, BK=64, 256 thr / 4 waves (2x2 quadrants of
// 64x64), global_load_lds dwordx4 staging into linear LDS [128][64].
// MODE 0: fp32 out [M][N]; MODE 1: bf16 [b,h,s,hd];
// MODE 2: bf16 [b,h,hd,s] via LDS-transposed epilogue (coalesced 256B rows —
//         the direct 2B/4KB-stride scatter was the write-amplification sink).
// ---------------------------------------------------------------------------
template <int MODE>
__global__ __launch_bounds__(256) void gemm_bf16_k(
    const bf16* __restrict__ A, const bf16* __restrict__ Bt,
    const float* __restrict__ bias, void* __restrict__ outv, float scale)
{
    constexpr int SM_ELEMS = (MODE == 2) ? (128 * 136) : (2 * 128 * 64);
    __shared__ __align__(16) bf16 smem[SM_ELEMS];
    bf16* const As = smem;               // [128][64]
    bf16* const Bs = smem + 128 * 64;    // [128][64]

    const int tid  = threadIdx.x;
    const int w    = tid >> 6;
    const int lane = tid & 63;
    const int quad = lane >> 4;
    const int l15  = lane & 15;
    const int m0   = blockIdx.x * 128;
    const int n0   = blockIdx.y * 128;
    const int wm   = w >> 1;           // wave quadrant (2x2 of 64x64)
    const int wn   = w & 1;

    // staging geometry: one wave-issue covers 8 rows (8 lanes/row, 16B/lane)
    const int srow = lane >> 3;            // 0..7 row within issue-group
    const int scol = (lane & 7) * 8;       // element col (16B per lane)

    f32x4 acc[4][4] = {};

    for (int k0 = 0; k0 < Dn; k0 += 64) {
        #pragma unroll
        for (int j = 0; j < 4; ++j) {
            const int rbase = (w * 4 + j) * 8;      // wave-uniform
            const int r = rbase + srow;
            __builtin_amdgcn_global_load_lds(
                (gvoid*)(A + (size_t)(m0 + r) * Dn + k0 + scol),
                (lvoid*)&As[rbase * 64], 16, 0, 0);
            __builtin_amdgcn_global_load_lds(
                (gvoid*)(Bt + (size_t)(n0 + r) * Dn + k0 + scol),
                (lvoid*)&Bs[rbase * 64], 16, 0, 0);
        }
        __syncthreads();   // drains vmcnt: staged data visible

        #pragma unroll
        for (int ks = 0; ks < 64; ks += 32) {
            bf16x8 af[4], bfr[4];
            #pragma unroll
            for (int fm = 0; fm < 4; ++fm)
                af[fm] = *(const bf16x8*)&As[(wm * 64 + fm * 16 + l15) * 64 + ks + quad * 8];
            #pragma unroll
            for (int fn = 0; fn < 4; ++fn)
                bfr[fn] = *(const bf16x8*)&Bs[(wn * 64 + fn * 16 + l15) * 64 + ks + quad * 8];
            #pragma unroll
            for (int fm = 0; fm < 4; ++fm)
                #pragma unroll
                for (int fn = 0; fn < 4; ++fn)
                    acc[fm][fn] = __builtin_amdgcn_mfma_f32_16x16x32_bf16(
                        af[fm], bfr[fn], acc[fm][fn], 0, 0, 0);
        }
        __syncthreads();
    }

    if (MODE == 2) {
        // Transpose through LDS: T[n][m] (pad 136), then coalesced rows of
        // Vt[b,h,hd,s] (256B contiguous per 16 lanes).
        bf16* const T = smem;    // reuse after final barrier
        #pragma unroll
        for (int fn = 0; fn < 4; ++fn) {
            const int n = wn * 64 + fn * 16 + l15;
            const float bv = bias[n0 + n];
            #pragma unroll
            for (int fm = 0; fm < 4; ++fm) {
                const int m = wm * 64 + fm * 16 + quad * 4;
                bf16x4 pk;
                #pragma unroll
                for (int i = 0; i < 4; ++i)
                    pk[i] = (bf16)((acc[fm][fn][i] + bv) * scale);
                *(bf16x4*)&T[n * 136 + m] = pk;
            }
        }
        __syncthreads();
        const int b  = m0 >> 11;
        const int s0 = m0 & (Sn - 1);
        #pragma unroll
        for (int it = 0; it < 8; ++it) {
            const int n    = it * 16 + (tid >> 4);       // 0..127
            const int mcol = (tid & 15) * 8;
            const int gh = (n0 + n) >> 6, ghd = (n0 + n) & 63;
            bf16x8 v = *(const bf16x8*)&T[n * 136 + mcol];
            *(bf16x8*)((bf16*)outv +
                (((size_t)(b * Hn + gh) * HDn) + ghd) * Sn + s0 + mcol) = v;
        }
    } else {
        #pragma unroll
        for (int fn = 0; fn < 4; ++fn) {
            const int c = n0 + wn * 64 + fn * 16 + l15;
            const float bv = bias[c];
            #pragma unroll
            for (int fm = 0; fm < 4; ++fm) {
                #pragma unroll
                for (int i = 0; i < 4; ++i) {
                    const int m = m0 + wm * 64 + fm * 16 + quad * 4 + i;
                    const float v = (acc[fm][fn][i] + bv) * scale;
                    if (MODE == 0) {
                        ((float*)outv)[(size_t)m * Dn + c] = v;
                    } else {
                        const int b = m >> 11, s = m & (Sn - 1);
                        const int h = c >> 6, hd = c & 63;
                        ((bf16*)outv)[(((size_t)(b * Hn + h) * Sn) + s) * HDn + hd] = (bf16)v;
                    }
                }
            }
        }
    }
}

// ---------------------------------------------------------------------------
// LDS XOR-swizzle (element-index form): 16B chunk column ^= row&7.
// ---------------------------------------------------------------------------
__device__ __forceinline__ int sidx(int r, int c) {
    return r * 64 + (c ^ ((r & 7) << 3));
}

// ---------------------------------------------------------------------------
// Flash attention, bf16 MFMA, swapped QK^T; per-lane q-row softmax in log2
// domain (0.125*log2e folded into Q at projection time). This revision:
//  - global_load_lds staging for K/Vt, pre-swizzled GLOBAL source so linear
//    DMA writes land XOR-swizzled (m173/m201 both-sides rule)
//  - true double-buffered K/V, ONE barrier per chunk: chunk t+1 loads fly
//    across all of chunk t's compute (T3-minimal)
//  - T13 defer-max (THR=8 in log2 domain): skip alpha/rescale when no row's
//    max grows — drops 1 exp2 + 8 bpermute + 16 mul on most iterations
// ---------------------------------------------------------------------------
__global__ __launch_bounds__(256) void attn_mfma_k(
    const bf16* __restrict__ Qb, const bf16* __restrict__ Kb,
    const bf16* __restrict__ Vtb, const int* __restrict__ kpm,
    const float* __restrict__ mod, bf16* __restrict__ att)
{
    __shared__ __align__(16) bf16 Ks[2][64 * 64];
    __shared__ __align__(16) bf16 Vts[2][64 * 64];
    __shared__ __align__(16) bf16 Ps[64 * 64];

    const int tid  = threadIdx.x;
    const int w    = tid >> 6;
    const int lane = tid & 63;
    const int quad = lane >> 4;
    const int l15  = lane & 15;
    const int blk  = blockIdx.x;
    const int bh   = blk >> 5;             // q-tile innermost: K/V L2-reuse
    const int q0   = (blk & 31) * 64;
    const int b    = bh >> 4;
    const int h    = bh & 15;
    const size_t base = (size_t)bh * Sn * HDn;

    const int qrow = q0 + w * 16 + l15;    // this lane's softmax q-row
    const bf16x8 qf0 = *(const bf16x8*)(Qb + base + (size_t)qrow * HDn + 0  + quad * 8);
    const bf16x8 qf1 = *(const bf16x8*)(Qb + base + (size_t)qrow * HDn + 32 + quad * 8);

    const bool qm = kpm[(size_t)b * Sn + qrow] != 0;
    const float* modrow = mod + ((size_t)b * Sn + qrow) * Sn;

    float m_r = -1e30f;
    float l_r = 0.0f;
    f32x4 O[4] = {};

    // DMA staging geometry: lane covers (row rl, phys chunk lane&7) of an
    // 8-row group; source chunk pre-swizzled so the linear LDS write lands
    // at the XOR-swizzled slot the readers expect.
    const int rl = lane >> 3;                       // 0..7
    const int cg = ((lane & 7) ^ rl) * 8;           // swizzled source elems

    auto stage = [&](int t, int buf) {
        const int k0 = t * 64;
        #pragma unroll
        for (int p = 0; p < 2; ++p) {
            const int gb = p * 32 + w * 8;          // group base row (mult 8)
            __builtin_amdgcn_global_load_lds(
                (gvoid*)(Kb + base + (size_t)(k0 + gb + rl) * HDn + cg),
                (lvoid*)&Ks[buf][gb * 64], 16, 0, 0);
            __builtin_amdgcn_global_load_lds(
                (gvoid*)(Vtb + base + (size_t)(gb + rl) * Sn + k0 + cg),
                (lvoid*)&Vts[buf][gb * 64], 16, 0, 0);
        }
    };

    // prologue: chunk 0 into buf 0; mod chunk 0 into regs
    stage(0, 0);
    float4 md[4];
    #pragma unroll
    for (int ct = 0; ct < 4; ++ct)
        md[ct] = *(const float4*)(modrow + ct * 16 + quad * 4);
    __syncthreads();

    constexpr int NT = Sn / 64;
    for (int t = 0; t < NT; ++t) {
        const int cur = t & 1;

        // issue next chunk's DMA + mod prefetch (fly across this compute)
        float4 mdn[4];
        if (t + 1 < NT) {
            stage(t + 1, cur ^ 1);
            #pragma unroll
            for (int ct = 0; ct < 4; ++ct)
                mdn[ct] = *(const float4*)(modrow + (t + 1) * 64 + ct * 16 + quad * 4);
        }

        // QK^T (swapped): lane holds e[k = ct*16+quad*4+i] for its q-row
        float e[4][4];
        #pragma unroll
        for (int ct = 0; ct < 4; ++ct) {
            f32x4 s = {};
            #pragma unroll
            for (int ks = 0; ks < 64; ks += 32) {
                bf16x8 kf = *(const bf16x8*)&Ks[cur][sidx(ct * 16 + l15, ks + quad * 8)];
                s = __builtin_amdgcn_mfma_f32_16x16x32_bf16(kf, ks ? qf1 : qf0, s, 0, 0, 0);
            }
            #pragma unroll
            for (int i = 0; i < 4; ++i)
                e[ct][i] = qm ? -1e10f : s[i] * (&md[ct].x)[i];
        }

        // row max: 15 in-reg fmax + 2 cross-quad shfl
        float pmax = e[0][0];
        #pragma unroll
        for (int ct = 0; ct < 4; ++ct)
            #pragma unroll
            for (int i = 0; i < 4; ++i)
                pmax = fmaxf(pmax, e[ct][i]);
        pmax = fmaxf(pmax, __shfl_xor(pmax, 16));
        pmax = fmaxf(pmax, __shfl_xor(pmax, 32));

        // T13 defer-max: only rescale when some row's max grew past THR=8
        if (__any(pmax > m_r + 8.0f)) {
            const float mnew  = fmaxf(m_r, pmax);
            const float alpha = __builtin_amdgcn_exp2f(m_r - mnew);
            m_r = mnew;
            l_r *= alpha;
            float aO[4];
            #pragma unroll
            for (int i = 0; i < 4; ++i)
                aO[i] = __shfl(alpha, quad * 4 + i, 16);
            #pragma unroll
            for (int ct = 0; ct < 4; ++ct)
                #pragma unroll
                for (int i = 0; i < 4; ++i)
                    O[ct][i] *= aO[i];
        }

        // P = exp2(e - m), bf16-rounded; [q][k] via ds_write_b64 (swizzled)
        float rs = 0.0f;
        #pragma unroll
        for (int ct = 0; ct < 4; ++ct) {
            bf16x4 pb;
            #pragma unroll
            for (int i = 0; i < 4; ++i) {
                const bf16 p = (bf16)__builtin_amdgcn_exp2f(e[ct][i] - m_r);
                pb[i] = p;
                rs += (float)p;
            }
            *(bf16x4*)&Ps[sidx(w * 16 + l15, ct * 16 + quad * 4)] = pb;
        }
        rs += __shfl_xor(rs, 16);
        rs += __shfl_xor(rs, 32);
        l_r += rs;

        // O += P V (Ps rows are wave-local; same-wave RAW via lgkmcnt)
        #pragma unroll
        for (int ks = 0; ks < 64; ks += 32) {
            bf16x8 paf = *(const bf16x8*)&Ps[sidx(w * 16 + l15, ks + quad * 8)];
            #pragma unroll
            for (int ct = 0; ct < 4; ++ct) {
                bf16x8 vf = *(const bf16x8*)&Vts[cur][sidx(ct * 16 + l15, ks + quad * 8)];
                O[ct] = __builtin_amdgcn_mfma_f32_16x16x32_bf16(paf, vf, O[ct], 0, 0, 0);
            }
        }

        if (t + 1 < NT) {
            #pragma unroll
            for (int ct = 0; ct < 4; ++ct)
                md[ct] = mdn[ct];
        }
        // ONE barrier: (a) all reads of buf cur done before t+1 overwrites it
        // next iter; (b) implicit vmcnt(0) drain => chunk t+1 DMA landed.
        __syncthreads();
    }

    float lO[4];
    #pragma unroll
    for (int i = 0; i < 4; ++i)
        lO[i] = 1.0f / __shfl(l_r, quad * 4 + i, 16);
    #pragma unroll
    for (int ct = 0; ct < 4; ++ct)
        #pragma unroll
        for (int i = 0; i < 4; ++i) {
            const int row = q0 + w * 16 + quad * 4 + i;
            const int col = h * HDn + ct * 16 + l15;
            att[((size_t)b * Sn + row) * Dn + col] = (bf16)(O[ct][i] * lO[i]);
        }
}

// ---------------------------------------------------------------------------
// Launch
// ---------------------------------------------------------------------------
extern "C" void kernel_launch(void* const* d_in, const int* in_sizes, int n_in,
                              void* d_out, int out_size, void* d_ws, size_t ws_size,
                              hipStream_t stream) {
    const float* x   = (const float*)d_in[0];
    const int*   kpm = (const int*)d_in[1];
    const float* mod = (const float*)d_in[2];
    const float* Wq  = (const float*)d_in[3];
    const float* bq  = (const float*)d_in[4];
    const float* Wk  = (const float*)d_in[5];
    const float* bk  = (const float*)d_in[6];
    const float* Wv  = (const float*)d_in[7];
    const float* bv  = (const float*)d_in[8];
    const float* Wo  = (const float*)d_in[9];
    const float* bo  = (const float*)d_in[10];
    float* out = (float*)d_out;

    // Workspace (all bf16): xb, qb, kb, vtb, attb (8.4M each) + 4 Wt (1M each)
    bf16* ws = (bf16*)d_ws;
    const size_t sz = (size_t)Bn * Sn * Dn;   // 8388608
    const size_t wz = (size_t)Dn * Dn;        // 1048576
    bf16* xb   = ws;
    bf16* qb   = ws + sz;
    bf16* kb   = ws + 2 * sz;
    bf16* vtb  = ws + 3 * sz;
    bf16* attb = ws + 4 * sz;
    bf16* wqt  = ws + 5 * sz;
    bf16* wkt  = wqt + wz;
    bf16* wvt  = wkt + wz;
    bf16* wot  = wvt + wz;

    conv_f32_bf16_k<<<(int)(sz / 1024), 256, 0, stream>>>(x, xb, (int)sz);
    conv_wt_k<<<dim3(16, 16, 4), 256, 0, stream>>>(Wq, Wk, Wv, Wo, wqt, wkt, wvt, wot);

    // 0.125 (1/sqrt(hd)) * log2(e): folded into Q so attn runs in log2 domain
    const float SC = 0.125f * 1.44269504088896340736f;

    const dim3 gemm_grid(64, 8);   // 128x128 tiles over 8192x1024
    gemm_bf16_k<1><<<gemm_grid, 256, 0, stream>>>(xb, wqt, bq, qb, SC);
    gemm_bf16_k<1><<<gemm_grid, 256, 0, stream>>>(xb, wkt, bk, kb, 1.0f);
    gemm_bf16_k<2><<<gemm_grid, 256, 0, stream>>>(xb, wvt, bv, vtb, 1.0f);

    attn_mfma_k<<<Bn * Hn * (Sn / 64), 256, 0, stream>>>(qb, kb, vtb, kpm, mod, attb);

    gemm_bf16_k<0><<<gemm_grid, 256, 0, stream>>>(attb, wot, bo, out, 1.0f);
}

// Round 5
// 437.510 us; speedup vs baseline: 1.0144x; 1.0144x over previous
//
#include <hip/hip_runtime.h>
#include <cstddef>

// Problem constants: B=4, S=2048, D=1024, H=16, HD=64
constexpr int Bn  = 4;
constexpr int Sn  = 2048;
constexpr int Dn  = 1024;
constexpr int Hn  = 16;
constexpr int HDn = 64;

typedef __bf16 bf16;
typedef __attribute__((ext_vector_type(8))) __bf16 bf16x8;
typedef __attribute__((ext_vector_type(4))) __bf16 bf16x4;
typedef __attribute__((ext_vector_type(4))) float  f32x4;

typedef __attribute__((address_space(1))) const void gvoid;
typedef __attribute__((address_space(3))) void lvoid;

// ---------------------------------------------------------------------------
// Elementwise fp32 -> bf16 (x staging)
// ---------------------------------------------------------------------------
__global__ __launch_bounds__(256) void conv_f32_bf16_k(
    const float* __restrict__ in, bf16* __restrict__ out, int n)
{
    int i = (blockIdx.x * 256 + threadIdx.x) * 4;
    if (i + 3 < n) {
        float4 v = *(const float4*)(in + i);
        bf16 o[4] = {(bf16)v.x, (bf16)v.y, (bf16)v.z, (bf16)v.w};
        *(ulong1*)(out + i) = *(ulong1*)o;  // 8B store
    }
}

// ---------------------------------------------------------------------------
// Bias concat: [bq|bk|bv] -> float[3072]
// ---------------------------------------------------------------------------
__global__ __launch_bounds__(256) void bias_cat_k(
    const float* __restrict__ bq, const float* __restrict__ bk,
    const float* __restrict__ bv, float* __restrict__ o)
{
    const int i = blockIdx.x * 256 + threadIdx.x;   // grid 12 -> 3072
    if (i < 1024)      o[i] = bq[i];
    else if (i < 2048) o[i] = bk[i - 1024];
    else if (i < 3072) o[i] = bv[i - 2048];
}

// ---------------------------------------------------------------------------
// Weight transpose + convert: W[k][n] fp32 -> Wt[n][k] bf16. 64x64 tiles.
// ---------------------------------------------------------------------------
__global__ __launch_bounds__(256) void conv_wt_k(
    const float* __restrict__ w0, const float* __restrict__ w1,
    const float* __restrict__ w2, const float* __restrict__ w3,
    bf16* __restrict__ o0, bf16* __restrict__ o1,
    bf16* __restrict__ o2, bf16* __restrict__ o3)
{
    const float* W = (blockIdx.z == 0) ? w0 : (blockIdx.z == 1) ? w1
                   : (blockIdx.z == 2) ? w2 : w3;
    bf16* O = (blockIdx.z == 0) ? o0 : (blockIdx.z == 1) ? o1
            : (blockIdx.z == 2) ? o2 : o3;
    __shared__ float t[64][65];
    const int tid = threadIdx.x;
    const int k0 = blockIdx.x * 64;   // row of W (k-dim)
    const int n0 = blockIdx.y * 64;   // col of W (n-dim)
    #pragma unroll
    for (int p = 0; p < 16; ++p) {
        const int idx = p * 256 + tid;
        const int r = idx >> 6, c = idx & 63;
        t[r][c] = W[(size_t)(k0 + r) * Dn + n0 + c];
    }
    __syncthreads();
    #pragma unroll
    for (int p = 0; p < 16; ++p) {
        const int idx = p * 256 + tid;
        const int r = idx >> 6, c = idx & 63;   // r: n-offset, c: k-offset
        O[(size_t)(n0 + r) * Dn + k0 + c] = (bf16)t[c][r];
    }
}

// ---------------------------------------------------------------------------
// Final-projection GEMM (m97 structure): out_f32 = A(8192x1024) @ Bt^T + bias.
// 128x128 tile, BK=64, 4 waves (2x2 quadrants of 64x64), global_load_lds.
// ---------------------------------------------------------------------------
__global__ __launch_bounds__(256) void gemm_out_k(
    const bf16* __restrict__ A, const bf16* __restrict__ Bt,
    const float* __restrict__ bias, float* __restrict__ outv)
{
    __shared__ __align__(16) bf16 smem[2 * 128 * 64];
    bf16* const As = smem;               // [128][64]
    bf16* const Bs = smem + 128 * 64;    // [128][64]

    const int tid  = threadIdx.x;
    const int w    = tid >> 6;
    const int lane = tid & 63;
    const int quad = lane >> 4;
    const int l15  = lane & 15;
    const int m0   = blockIdx.x * 128;
    const int n0   = blockIdx.y * 128;
    const int wm   = w >> 1;
    const int wn   = w & 1;

    const int srow = lane >> 3;
    const int scol = (lane & 7) * 8;

    f32x4 acc[4][4] = {};

    for (int k0 = 0; k0 < Dn; k0 += 64) {
        #pragma unroll
        for (int j = 0; j < 4; ++j) {
            const int rbase = (w * 4 + j) * 8;
            const int r = rbase + srow;
            __builtin_amdgcn_global_load_lds(
                (gvoid*)(A + (size_t)(m0 + r) * Dn + k0 + scol),
                (lvoid*)&As[rbase * 64], 16, 0, 0);
            __builtin_amdgcn_global_load_lds(
                (gvoid*)(Bt + (size_t)(n0 + r) * Dn + k0 + scol),
                (lvoid*)&Bs[rbase * 64], 16, 0, 0);
        }
        __syncthreads();

        #pragma unroll
        for (int ks = 0; ks < 64; ks += 32) {
            bf16x8 af[4], bfr[4];
            #pragma unroll
            for (int fm = 0; fm < 4; ++fm)
                af[fm] = *(const bf16x8*)&As[(wm * 64 + fm * 16 + l15) * 64 + ks + quad * 8];
            #pragma unroll
            for (int fn = 0; fn < 4; ++fn)
                bfr[fn] = *(const bf16x8*)&Bs[(wn * 64 + fn * 16 + l15) * 64 + ks + quad * 8];
            #pragma unroll
            for (int fm = 0; fm < 4; ++fm)
                #pragma unroll
                for (int fn = 0; fn < 4; ++fn)
                    acc[fm][fn] = __builtin_amdgcn_mfma_f32_16x16x32_bf16(
                        af[fm], bfr[fn], acc[fm][fn], 0, 0, 0);
        }
        __syncthreads();
    }

    #pragma unroll
    for (int fn = 0; fn < 4; ++fn) {
        const int c = n0 + wn * 64 + fn * 16 + l15;
        const float bv = bias[c];
        #pragma unroll
        for (int fm = 0; fm < 4; ++fm)
            #pragma unroll
            for (int i = 0; i < 4; ++i) {
                const int m = m0 + wm * 64 + fm * 16 + quad * 4 + i;
                outv[(size_t)m * Dn + c] = acc[fm][fn][i] + bv;
            }
    }
}

// ---------------------------------------------------------------------------
// FUSED QKV GEMM: A(8192x1024) @ Wqkv^T(3072x1024) + bias_cat, grid 64x24
// (1536 blocks, 6/CU -- 3x the blocks-in-flight of the split version, and A
// is fetched once instead of 3x). Same verified m97 inner loop. Epilogue is
// block-uniform on section = n0>>10:
//   sec 0 (Q): bf16 [b,h,s,hd], scaled by scq (0.125*log2e folded here)
//   sec 1 (K): bf16 [b,h,s,hd]
//   sec 2 (V): bf16 [b,h,hd,s] via LDS-transposed coalesced store
// ---------------------------------------------------------------------------
__global__ __launch_bounds__(256) void gemm_qkv_k(
    const bf16* __restrict__ A, const bf16* __restrict__ Wt,
    const float* __restrict__ bias, bf16* __restrict__ qout,
    bf16* __restrict__ kout, bf16* __restrict__ vout, float scq)
{
    __shared__ __align__(16) bf16 smem[128 * 136];   // As+Bs (16384) / V-transpose T
    bf16* const As = smem;               // [128][64]
    bf16* const Bs = smem + 128 * 64;    // [128][64]

    const int tid  = threadIdx.x;
    const int w    = tid >> 6;
    const int lane = tid & 63;
    const int quad = lane >> 4;
    const int l15  = lane & 15;
    const int m0   = blockIdx.x * 128;
    const int n0   = blockIdx.y * 128;   // in [0, 3072)
    const int wm   = w >> 1;
    const int wn   = w & 1;

    const int srow = lane >> 3;
    const int scol = (lane & 7) * 8;

    f32x4 acc[4][4] = {};

    for (int k0 = 0; k0 < Dn; k0 += 64) {
        #pragma unroll
        for (int j = 0; j < 4; ++j) {
            const int rbase = (w * 4 + j) * 8;
            const int r = rbase + srow;
            __builtin_amdgcn_global_load_lds(
                (gvoid*)(A + (size_t)(m0 + r) * Dn + k0 + scol),
                (lvoid*)&As[rbase * 64], 16, 0, 0);
            __builtin_amdgcn_global_load_lds(
                (gvoid*)(Wt + (size_t)(n0 + r) * Dn + k0 + scol),
                (lvoid*)&Bs[rbase * 64], 16, 0, 0);
        }
        __syncthreads();

        #pragma unroll
        for (int ks = 0; ks < 64; ks += 32) {
            bf16x8 af[4], bfr[4];
            #pragma unroll
            for (int fm = 0; fm < 4; ++fm)
                af[fm] = *(const bf16x8*)&As[(wm * 64 + fm * 16 + l15) * 64 + ks + quad * 8];
            #pragma unroll
            for (int fn = 0; fn < 4; ++fn)
                bfr[fn] = *(const bf16x8*)&Bs[(wn * 64 + fn * 16 + l15) * 64 + ks + quad * 8];
            #pragma unroll
            for (int fm = 0; fm < 4; ++fm)
                #pragma unroll
                for (int fn = 0; fn < 4; ++fn)
                    acc[fm][fn] = __builtin_amdgcn_mfma_f32_16x16x32_bf16(
                        af[fm], bfr[fn], acc[fm][fn], 0, 0, 0);
        }
        __syncthreads();
    }

    const int sec = n0 >> 10;            // 0=Q, 1=K, 2=V (block-uniform)
    const int cb  = n0 & 1023;           // column base within the section

    if (sec < 2) {
        bf16* const outp = sec ? kout : qout;
        const float scale = sec ? 1.0f : scq;
        #pragma unroll
        for (int fn = 0; fn < 4; ++fn) {
            const int cc = cb + wn * 64 + fn * 16 + l15;
            const float bv = bias[n0 + wn * 64 + fn * 16 + l15];
            const int h = cc >> 6, hd = cc & 63;
            #pragma unroll
            for (int fm = 0; fm < 4; ++fm)
                #pragma unroll
                for (int i = 0; i < 4; ++i) {
                    const int m = m0 + wm * 64 + fm * 16 + quad * 4 + i;
                    const int b = m >> 11, s = m & (Sn - 1);
                    outp[(((size_t)(b * Hn + h) * Sn) + s) * HDn + hd] =
                        (bf16)((acc[fm][fn][i] + bv) * scale);
                }
        }
    } else {
        // V: transpose through LDS (pad 136), then coalesced 256B row stores.
        bf16* const T = smem;    // reuse after final barrier of the main loop
        #pragma unroll
        for (int fn = 0; fn < 4; ++fn) {
            const int n = wn * 64 + fn * 16 + l15;
            const float bv = bias[n0 + n];
            #pragma unroll
            for (int fm = 0; fm < 4; ++fm) {
                const int m = wm * 64 + fm * 16 + quad * 4;
                bf16x4 pk;
                #pragma unroll
                for (int i = 0; i < 4; ++i)
                    pk[i] = (bf16)(acc[fm][fn][i] + bv);
                *(bf16x4*)&T[n * 136 + m] = pk;
            }
        }
        __syncthreads();
        const int b  = m0 >> 11;
        const int s0 = m0 & (Sn - 1);
        #pragma unroll
        for (int it = 0; it < 8; ++it) {
            const int n    = it * 16 + (tid >> 4);       // 0..127
            const int mcol = (tid & 15) * 8;
            const int gh = (cb + n) >> 6, ghd = (cb + n) & 63;
            bf16x8 v = *(const bf16x8*)&T[n * 136 + mcol];
            *(bf16x8*)(vout +
                (((size_t)(b * Hn + gh) * HDn) + ghd) * Sn + s0 + mcol) = v;
        }
    }
}

// ---------------------------------------------------------------------------
// LDS XOR-swizzle (element-index form): 16B chunk column ^= row&7.
// ---------------------------------------------------------------------------
__device__ __forceinline__ int sidx(int r, int c) {
    return r * 64 + (c ^ ((r & 7) << 3));
}

// ---------------------------------------------------------------------------
// Flash attention (unchanged from R4-passing version): bf16 MFMA, swapped
// QK^T, per-lane q-row softmax in log2 domain, DMA-staged double-buffered
// K/Vt with pre-swizzled global source, T13 defer-max.
// ---------------------------------------------------------------------------
__global__ __launch_bounds__(256) void attn_mfma_k(
    const bf16* __restrict__ Qb, const bf16* __restrict__ Kb,
    const bf16* __restrict__ Vtb, const int* __restrict__ kpm,
    const float* __restrict__ mod, bf16* __restrict__ att)
{
    __shared__ __align__(16) bf16 Ks[2][64 * 64];
    __shared__ __align__(16) bf16 Vts[2][64 * 64];
    __shared__ __align__(16) bf16 Ps[64 * 64];

    const int tid  = threadIdx.x;
    const int w    = tid >> 6;
    const int lane = tid & 63;
    const int quad = lane >> 4;
    const int l15  = lane & 15;
    const int blk  = blockIdx.x;
    const int bh   = blk >> 5;             // q-tile innermost: K/V L2-reuse
    const int q0   = (blk & 31) * 64;
    const int b    = bh >> 4;
    const int h    = bh & 15;
    const size_t base = (size_t)bh * Sn * HDn;

    const int qrow = q0 + w * 16 + l15;    // this lane's softmax q-row
    const bf16x8 qf0 = *(const bf16x8*)(Qb + base + (size_t)qrow * HDn + 0  + quad * 8);
    const bf16x8 qf1 = *(const bf16x8*)(Qb + base + (size_t)qrow * HDn + 32 + quad * 8);

    const bool qm = kpm[(size_t)b * Sn + qrow] != 0;
    const float* modrow = mod + ((size_t)b * Sn + qrow) * Sn;

    float m_r = -1e30f;
    float l_r = 0.0f;
    f32x4 O[4] = {};

    const int rl = lane >> 3;                       // 0..7
    const int cg = ((lane & 7) ^ rl) * 8;           // swizzled source elems

    auto stage = [&](int t, int buf) {
        const int k0 = t * 64;
        #pragma unroll
        for (int p = 0; p < 2; ++p) {
            const int gb = p * 32 + w * 8;          // group base row (mult 8)
            __builtin_amdgcn_global_load_lds(
                (gvoid*)(Kb + base + (size_t)(k0 + gb + rl) * HDn + cg),
                (lvoid*)&Ks[buf][gb * 64], 16, 0, 0);
            __builtin_amdgcn_global_load_lds(
                (gvoid*)(Vtb + base + (size_t)(gb + rl) * Sn + k0 + cg),
                (lvoid*)&Vts[buf][gb * 64], 16, 0, 0);
        }
    };

    stage(0, 0);
    float4 md[4];
    #pragma unroll
    for (int ct = 0; ct < 4; ++ct)
        md[ct] = *(const float4*)(modrow + ct * 16 + quad * 4);
    __syncthreads();

    constexpr int NT = Sn / 64;
    for (int t = 0; t < NT; ++t) {
        const int cur = t & 1;

        float4 mdn[4];
        if (t + 1 < NT) {
            stage(t + 1, cur ^ 1);
            #pragma unroll
            for (int ct = 0; ct < 4; ++ct)
                mdn[ct] = *(const float4*)(modrow + (t + 1) * 64 + ct * 16 + quad * 4);
        }

        float e[4][4];
        #pragma unroll
        for (int ct = 0; ct < 4; ++ct) {
            f32x4 s = {};
            #pragma unroll
            for (int ks = 0; ks < 64; ks += 32) {
                bf16x8 kf = *(const bf16x8*)&Ks[cur][sidx(ct * 16 + l15, ks + quad * 8)];
                s = __builtin_amdgcn_mfma_f32_16x16x32_bf16(kf, ks ? qf1 : qf0, s, 0, 0, 0);
            }
            #pragma unroll
            for (int i = 0; i < 4; ++i)
                e[ct][i] = qm ? -1e10f : s[i] * (&md[ct].x)[i];
        }

        float pmax = e[0][0];
        #pragma unroll
        for (int ct = 0; ct < 4; ++ct)
            #pragma unroll
            for (int i = 0; i < 4; ++i)
                pmax = fmaxf(pmax, e[ct][i]);
        pmax = fmaxf(pmax, __shfl_xor(pmax, 16));
        pmax = fmaxf(pmax, __shfl_xor(pmax, 32));

        if (__any(pmax > m_r + 8.0f)) {
            const float mnew  = fmaxf(m_r, pmax);
            const float alpha = __builtin_amdgcn_exp2f(m_r - mnew);
            m_r = mnew;
            l_r *= alpha;
            float aO[4];
            #pragma unroll
            for (int i = 0; i < 4; ++i)
                aO[i] = __shfl(alpha, quad * 4 + i, 16);
            #pragma unroll
            for (int ct = 0; ct < 4; ++ct)
                #pragma unroll
                for (int i = 0; i < 4; ++i)
                    O[ct][i] *= aO[i];
        }

        float rs = 0.0f;
        #pragma unroll
        for (int ct = 0; ct < 4; ++ct) {
            bf16x4 pb;
            #pragma unroll
            for (int i = 0; i < 4; ++i) {
                const bf16 p = (bf16)__builtin_amdgcn_exp2f(e[ct][i] - m_r);
                pb[i] = p;
                rs += (float)p;
            }
            *(bf16x4*)&Ps[sidx(w * 16 + l15, ct * 16 + quad * 4)] = pb;
        }
        rs += __shfl_xor(rs, 16);
        rs += __shfl_xor(rs, 32);
        l_r += rs;

        #pragma unroll
        for (int ks = 0; ks < 64; ks += 32) {
            bf16x8 paf = *(const bf16x8*)&Ps[sidx(w * 16 + l15, ks + quad * 8)];
            #pragma unroll
            for (int ct = 0; ct < 4; ++ct) {
                bf16x8 vf = *(const bf16x8*)&Vts[cur][sidx(ct * 16 + l15, ks + quad * 8)];
                O[ct] = __builtin_amdgcn_mfma_f32_16x16x32_bf16(paf, vf, O[ct], 0, 0, 0);
            }
        }

        if (t + 1 < NT) {
            #pragma unroll
            for (int ct = 0; ct < 4; ++ct)
                md[ct] = mdn[ct];
        }
        __syncthreads();
    }

    float lO[4];
    #pragma unroll
    for (int i = 0; i < 4; ++i)
        lO[i] = 1.0f / __shfl(l_r, quad * 4 + i, 16);
    #pragma unroll
    for (int ct = 0; ct < 4; ++ct)
        #pragma unroll
        for (int i = 0; i < 4; ++i) {
            const int row = q0 + w * 16 + quad * 4 + i;
            const int col = h * HDn + ct * 16 + l15;
            att[((size_t)b * Sn + row) * Dn + col] = (bf16)(O[ct][i] * lO[i]);
        }
}

// ---------------------------------------------------------------------------
// Launch
// ---------------------------------------------------------------------------
extern "C" void kernel_launch(void* const* d_in, const int* in_sizes, int n_in,
                              void* d_out, int out_size, void* d_ws, size_t ws_size,
                              hipStream_t stream) {
    const float* x   = (const float*)d_in[0];
    const int*   kpm = (const int*)d_in[1];
    const float* mod = (const float*)d_in[2];
    const float* Wq  = (const float*)d_in[3];
    const float* bq  = (const float*)d_in[4];
    const float* Wk  = (const float*)d_in[5];
    const float* bk  = (const float*)d_in[6];
    const float* Wv  = (const float*)d_in[7];
    const float* bv  = (const float*)d_in[8];
    const float* Wo  = (const float*)d_in[9];
    const float* bo  = (const float*)d_in[10];
    float* out = (float*)d_out;

    // Workspace (bf16 unless noted): xb,qb,kb,vtb,attb (8.4M each) +
    // wqt|wkt|wvt|wot (1M each, contiguous -> wqt is Wqkv^T [3072][1024]) +
    // bqkv (3072 f32)
    bf16* ws = (bf16*)d_ws;
    const size_t sz = (size_t)Bn * Sn * Dn;   // 8388608
    const size_t wz = (size_t)Dn * Dn;        // 1048576
    bf16* xb   = ws;
    bf16* qb   = ws + sz;
    bf16* kb   = ws + 2 * sz;
    bf16* vtb  = ws + 3 * sz;
    bf16* attb = ws + 4 * sz;
    bf16* wqt  = ws + 5 * sz;
    bf16* wkt  = wqt + wz;
    bf16* wvt  = wkt + wz;
    bf16* wot  = wvt + wz;
    float* bqkv = (float*)(wot + wz);

    conv_f32_bf16_k<<<(int)(sz / 1024), 256, 0, stream>>>(x, xb, (int)sz);
    conv_wt_k<<<dim3(16, 16, 4), 256, 0, stream>>>(Wq, Wk, Wv, Wo, wqt, wkt, wvt, wot);
    bias_cat_k<<<12, 256, 0, stream>>>(bq, bk, bv, bqkv);

    // 0.125 (1/sqrt(hd)) * log2(e): folded into Q so attn runs in log2 domain
    const float SC = 0.125f * 1.44269504088896340736f;

    // Fused QKV: M=8192, N=3072, K=1024 -> grid 64x24 = 1536 blocks (6/CU)
    gemm_qkv_k<<<dim3(64, 24), 256, 0, stream>>>(xb, wqt, bqkv, qb, kb, vtb, SC);

    attn_mfma_k<<<Bn * Hn * (Sn / 64), 256, 0, stream>>>(qb, kb, vtb, kpm, mod, attb);

    gemm_out_k<<<dim3(64, 8), 256, 0, stream>>>(attb, wot, bo, out);
}

// Round 8
// 420.711 us; speedup vs baseline: 1.0549x; 1.0399x over previous
//
#include <hip/hip_runtime.h>
#include <cstddef>

// Problem constants: B=4, S=2048, D=1024, H=16, HD=64
constexpr int Bn  = 4;
constexpr int Sn  = 2048;
constexpr int Dn  = 1024;
constexpr int Hn  = 16;
constexpr int HDn = 64;

typedef __bf16 bf16;
typedef __attribute__((ext_vector_type(8))) __bf16 bf16x8;
typedef __attribute__((ext_vector_type(4))) __bf16 bf16x4;
typedef __attribute__((ext_vector_type(4))) float  f32x4;

typedef __attribute__((address_space(1))) const void gvoid;
typedef __attribute__((address_space(3))) void lvoid;

// ---------------------------------------------------------------------------
// Elementwise fp32 -> bf16 (x staging)
// ---------------------------------------------------------------------------
__global__ __launch_bounds__(256) void conv_f32_bf16_k(
    const float* __restrict__ in, bf16* __restrict__ out, int n)
{
    int i = (blockIdx.x * 256 + threadIdx.x) * 4;
    if (i + 3 < n) {
        float4 v = *(const float4*)(in + i);
        bf16 o[4] = {(bf16)v.x, (bf16)v.y, (bf16)v.z, (bf16)v.w};
        *(ulong1*)(out + i) = *(ulong1*)o;  // 8B store
    }
}

// ---------------------------------------------------------------------------
// Bias concat: [bq|bk|bv] -> float[3072]
// ---------------------------------------------------------------------------
__global__ __launch_bounds__(256) void bias_cat_k(
    const float* __restrict__ bq, const float* __restrict__ bk,
    const float* __restrict__ bv, float* __restrict__ o)
{
    const int i = blockIdx.x * 256 + threadIdx.x;   // grid 12 -> 3072
    if (i < 1024)      o[i] = bq[i];
    else if (i < 2048) o[i] = bk[i - 1024];
    else if (i < 3072) o[i] = bv[i - 2048];
}

// ---------------------------------------------------------------------------
// Weight transpose + convert: W[k][n] fp32 -> Wt[n][k] bf16. 64x64 tiles.
// ---------------------------------------------------------------------------
__global__ __launch_bounds__(256) void conv_wt_k(
    const float* __restrict__ w0, const float* __restrict__ w1,
    const float* __restrict__ w2, const float* __restrict__ w3,
    bf16* __restrict__ o0, bf16* __restrict__ o1,
    bf16* __restrict__ o2, bf16* __restrict__ o3)
{
    const float* W = (blockIdx.z == 0) ? w0 : (blockIdx.z == 1) ? w1
                   : (blockIdx.z == 2) ? w2 : w3;
    bf16* O = (blockIdx.z == 0) ? o0 : (blockIdx.z == 1) ? o1
            : (blockIdx.z == 2) ? o2 : o3;
    __shared__ float t[64][65];
    const int tid = threadIdx.x;
    const int k0 = blockIdx.x * 64;   // row of W (k-dim)
    const int n0 = blockIdx.y * 64;   // col of W (n-dim)
    #pragma unroll
    for (int p = 0; p < 16; ++p) {
        const int idx = p * 256 + tid;
        const int r = idx >> 6, c = idx & 63;
        t[r][c] = W[(size_t)(k0 + r) * Dn + n0 + c];
    }
    __syncthreads();
    #pragma unroll
    for (int p = 0; p < 16; ++p) {
        const int idx = p * 256 + tid;
        const int r = idx >> 6, c = idx & 63;   // r: n-offset, c: k-offset
        O[(size_t)(n0 + r) * Dn + k0 + c] = (bf16)t[c][r];
    }
}

// ---------------------------------------------------------------------------
// 2-PHASE double-buffered MFMA GEMM (T3-minimum recipe, ref m228d: 622 TF):
//   stage(t+1 -> buf^1) issued BEFORE compute(buf); ONE vmcnt(0)+barrier per
//   K-tile. Stage latency hides under the 32-MFMA compute phase instead of
//   being serially exposed (the R5 diagnosis of the ~390 TF GEMM rate).
// 128x128 tile, BK=64, 4 waves (2x2 of 64x64), global_load_lds dwordx4,
// linear LDS (T2 measured-null at 2-phase). LDS 64 KB -> 2 blocks/CU.
// ---------------------------------------------------------------------------
#define GEMM_STAGE(Ap, Bp, k0, boff)                                          \
    {                                                                         \
        _Pragma("unroll")                                                     \
        for (int j = 0; j < 4; ++j) {                                         \
            const int rbase = (w * 4 + j) * 8;                                \
            const int r = rbase + srow;                                       \
            __builtin_amdgcn_global_load_lds(                                 \
                (gvoid*)(Ap + (size_t)(m0 + r) * Dn + (k0) + scol),           \
                (lvoid*)&smem[(boff) + rbase * 64], 16, 0, 0);                \
            __builtin_amdgcn_global_load_lds(                                 \
                (gvoid*)(Bp + (size_t)(n0 + r) * Dn + (k0) + scol),           \
                (lvoid*)&smem[(boff) + 128 * 64 + rbase * 64], 16, 0, 0);     \
        }                                                                     \
    }

#define GEMM_COMPUTE(boff)                                                    \
    {                                                                         \
        _Pragma("unroll")                                                     \
        for (int ks = 0; ks < 64; ks += 32) {                                 \
            bf16x8 af[4], bfr[4];                                             \
            _Pragma("unroll")                                                 \
            for (int fm = 0; fm < 4; ++fm)                                    \
                af[fm] = *(const bf16x8*)&smem[(boff) +                       \
                    (wm * 64 + fm * 16 + l15) * 64 + ks + quad * 8];          \
            _Pragma("unroll")                                                 \
            for (int fn = 0; fn < 4; ++fn)                                    \
                bfr[fn] = *(const bf16x8*)&smem[(boff) + 128 * 64 +           \
                    (wn * 64 + fn * 16 + l15) * 64 + ks + quad * 8];          \
            _Pragma("unroll")                                                 \
            for (int fm = 0; fm < 4; ++fm)                                    \
                _Pragma("unroll")                                             \
                for (int fn = 0; fn < 4; ++fn)                                \
                    acc[fm][fn] = __builtin_amdgcn_mfma_f32_16x16x32_bf16(    \
                        af[fm], bfr[fn], acc[fm][fn], 0, 0, 0);               \
        }                                                                     \
    }

constexpr int BUF = 2 * 128 * 64;   // elements per (A,B) buffer pair

// ---------------------------------------------------------------------------
// Final-projection GEMM: out_f32 = A(8192x1024) @ Bt^T + bias.
// ---------------------------------------------------------------------------
__global__ __launch_bounds__(256) void gemm_out_k(
    const bf16* __restrict__ A, const bf16* __restrict__ Bt,
    const float* __restrict__ bias, float* __restrict__ outv)
{
    __shared__ __align__(16) bf16 smem[2 * BUF];

    const int tid  = threadIdx.x;
    const int w    = tid >> 6;
    const int lane = tid & 63;
    const int quad = lane >> 4;
    const int l15  = lane & 15;
    const int m0   = blockIdx.x * 128;
    const int n0   = blockIdx.y * 128;
    const int wm   = w >> 1;
    const int wn   = w & 1;
    const int srow = lane >> 3;
    const int scol = (lane & 7) * 8;

    f32x4 acc[4][4] = {};

    GEMM_STAGE(A, Bt, 0, 0);
    __syncthreads();

    int boff = 0;
    for (int kt = 0; kt < Dn / 64; ++kt) {
        if (kt + 1 < Dn / 64) GEMM_STAGE(A, Bt, (kt + 1) * 64, boff ^ BUF);
        GEMM_COMPUTE(boff);
        __syncthreads();   // lgkm: buf reads done; vmcnt: next stage landed
        boff ^= BUF;
    }

    #pragma unroll
    for (int fn = 0; fn < 4; ++fn) {
        const int c = n0 + wn * 64 + fn * 16 + l15;
        const float bv = bias[c];
        #pragma unroll
        for (int fm = 0; fm < 4; ++fm)
            #pragma unroll
            for (int i = 0; i < 4; ++i) {
                const int m = m0 + wm * 64 + fm * 16 + quad * 4 + i;
                outv[(size_t)m * Dn + c] = acc[fm][fn][i] + bv;
            }
    }
}

// ---------------------------------------------------------------------------
// FUSED QKV GEMM: A(8192x1024) @ Wqkv^T(3072x1024) + bias_cat, grid 64x24.
// Epilogue block-uniform on section = n0>>10:
//   sec 0 (Q): bf16 [b,h,s,hd] scaled by scq; sec 1 (K): bf16 [b,h,s,hd];
//   sec 2 (V): bf16 [b,h,hd,s] via LDS-transposed coalesced store.
// ---------------------------------------------------------------------------
__global__ __launch_bounds__(256) void gemm_qkv_k(
    const bf16* __restrict__ A, const bf16* __restrict__ Wt,
    const float* __restrict__ bias, bf16* __restrict__ qout,
    bf16* __restrict__ kout, bf16* __restrict__ vout, float scq)
{
    __shared__ __align__(16) bf16 smem[2 * BUF];   // 64KB; V-transpose reuses

    const int tid  = threadIdx.x;
    const int w    = tid >> 6;
    const int lane = tid & 63;
    const int quad = lane >> 4;
    const int l15  = lane & 15;
    const int m0   = blockIdx.x * 128;
    const int n0   = blockIdx.y * 128;   // in [0, 3072)
    const int wm   = w >> 1;
    const int wn   = w & 1;
    const int srow = lane >> 3;
    const int scol = (lane & 7) * 8;

    f32x4 acc[4][4] = {};

    GEMM_STAGE(A, Wt, 0, 0);
    __syncthreads();

    int boff = 0;
    for (int kt = 0; kt < Dn / 64; ++kt) {
        if (kt + 1 < Dn / 64) GEMM_STAGE(A, Wt, (kt + 1) * 64, boff ^ BUF);
        GEMM_COMPUTE(boff);
        __syncthreads();
        boff ^= BUF;
    }

    const int sec = n0 >> 10;            // 0=Q, 1=K, 2=V (block-uniform)
    const int cb  = n0 & 1023;           // column base within the section

    if (sec < 2) {
        bf16* const outp = sec ? kout : qout;
        const float scale = sec ? 1.0f : scq;
        #pragma unroll
        for (int fn = 0; fn < 4; ++fn) {
            const int cc = cb + wn * 64 + fn * 16 + l15;
            const float bv = bias[n0 + wn * 64 + fn * 16 + l15];
            const int h = cc >> 6, hd = cc & 63;
            #pragma unroll
            for (int fm = 0; fm < 4; ++fm)
                #pragma unroll
                for (int i = 0; i < 4; ++i) {
                    const int m = m0 + wm * 64 + fm * 16 + quad * 4 + i;
                    const int b = m >> 11, s = m & (Sn - 1);
                    outp[(((size_t)(b * Hn + h) * Sn) + s) * HDn + hd] =
                        (bf16)((acc[fm][fn][i] + bv) * scale);
                }
        }
    } else {
        // V: transpose through LDS (pad 136), then coalesced 256B row stores.
        bf16* const T = smem;    // reuse after final barrier of the main loop
        #pragma unroll
        for (int fn = 0; fn < 4; ++fn) {
            const int n = wn * 64 + fn * 16 + l15;
            const float bv = bias[n0 + n];
            #pragma unroll
            for (int fm = 0; fm < 4; ++fm) {
                const int m = wm * 64 + fm * 16 + quad * 4;
                bf16x4 pk;
                #pragma unroll
                for (int i = 0; i < 4; ++i)
                    pk[i] = (bf16)(acc[fm][fn][i] + bv);
                *(bf16x4*)&T[n * 136 + m] = pk;
            }
        }
        __syncthreads();
        const int b  = m0 >> 11;
        const int s0 = m0 & (Sn - 1);
        #pragma unroll
        for (int it = 0; it < 8; ++it) {
            const int n    = it * 16 + (tid >> 4);       // 0..127
            const int mcol = (tid & 15) * 8;
            const int gh = (cb + n) >> 6, ghd = (cb + n) & 63;
            bf16x8 v = *(const bf16x8*)&T[n * 136 + mcol];
            *(bf16x8*)(vout +
                (((size_t)(b * Hn + gh) * HDn) + ghd) * Sn + s0 + mcol) = v;
        }
    }
}

// ---------------------------------------------------------------------------
// LDS XOR-swizzle (element-index form): 16B chunk column ^= row&7.
// ---------------------------------------------------------------------------
__device__ __forceinline__ int sidx(int r, int c) {
    return r * 64 + (c ^ ((r & 7) << 3));
}

// ---------------------------------------------------------------------------
// Flash attention (FROZEN from R4/R5-passing version): bf16 MFMA, swapped
// QK^T, per-lane q-row softmax in log2 domain, DMA-staged double-buffered
// K/Vt with pre-swizzled global source, T13 defer-max.
// ---------------------------------------------------------------------------
__global__ __launch_bounds__(256) void attn_mfma_k(
    const bf16* __restrict__ Qb, const bf16* __restrict__ Kb,
    const bf16* __restrict__ Vtb, const int* __restrict__ kpm,
    const float* __restrict__ mod, bf16* __restrict__ att)
{
    __shared__ __align__(16) bf16 Ks[2][64 * 64];
    __shared__ __align__(16) bf16 Vts[2][64 * 64];
    __shared__ __align__(16) bf16 Ps[64 * 64];

    const int tid  = threadIdx.x;
    const int w    = tid >> 6;
    const int lane = tid & 63;
    const int quad = lane >> 4;
    const int l15  = lane & 15;
    const int blk  = blockIdx.x;
    const int bh   = blk >> 5;             // q-tile innermost: K/V L2-reuse
    const int q0   = (blk & 31) * 64;
    const int b    = bh >> 4;
    const int h    = bh & 15;
    const size_t base = (size_t)bh * Sn * HDn;

    const int qrow = q0 + w * 16 + l15;    // this lane's softmax q-row
    const bf16x8 qf0 = *(const bf16x8*)(Qb + base + (size_t)qrow * HDn + 0  + quad * 8);
    const bf16x8 qf1 = *(const bf16x8*)(Qb + base + (size_t)qrow * HDn + 32 + quad * 8);

    const bool qm = kpm[(size_t)b * Sn + qrow] != 0;
    const float* modrow = mod + ((size_t)b * Sn + qrow) * Sn;

    float m_r = -1e30f;
    float l_r = 0.0f;
    f32x4 O[4] = {};

    const int rl = lane >> 3;                       // 0..7
    const int cg = ((lane & 7) ^ rl) * 8;           // swizzled source elems

    auto stage = [&](int t, int buf) {
        const int k0 = t * 64;
        #pragma unroll
        for (int p = 0; p < 2; ++p) {
            const int gb = p * 32 + w * 8;          // group base row (mult 8)
            __builtin_amdgcn_global_load_lds(
                (gvoid*)(Kb + base + (size_t)(k0 + gb + rl) * HDn + cg),
                (lvoid*)&Ks[buf][gb * 64], 16, 0, 0);
            __builtin_amdgcn_global_load_lds(
                (gvoid*)(Vtb + base + (size_t)(gb + rl) * Sn + k0 + cg),
                (lvoid*)&Vts[buf][gb * 64], 16, 0, 0);
        }
    };

    stage(0, 0);
    float4 md[4];
    #pragma unroll
    for (int ct = 0; ct < 4; ++ct)
        md[ct] = *(const float4*)(modrow + ct * 16 + quad * 4);
    __syncthreads();

    constexpr int NT = Sn / 64;
    for (int t = 0; t < NT; ++t) {
        const int cur = t & 1;

        float4 mdn[4];
        if (t + 1 < NT) {
            stage(t + 1, cur ^ 1);
            #pragma unroll
            for (int ct = 0; ct < 4; ++ct)
                mdn[ct] = *(const float4*)(modrow + (t + 1) * 64 + ct * 16 + quad * 4);
        }

        float e[4][4];
        #pragma unroll
        for (int ct = 0; ct < 4; ++ct) {
            f32x4 s = {};
            #pragma unroll
            for (int ks = 0; ks < 64; ks += 32) {
                bf16x8 kf = *(const bf16x8*)&Ks[cur][sidx(ct * 16 + l15, ks + quad * 8)];
                s = __builtin_amdgcn_mfma_f32_16x16x32_bf16(kf, ks ? qf1 : qf0, s, 0, 0, 0);
            }
            #pragma unroll
            for (int i = 0; i < 4; ++i)
                e[ct][i] = qm ? -1e10f : s[i] * (&md[ct].x)[i];
        }

        float pmax = e[0][0];
        #pragma unroll
        for (int ct = 0; ct < 4; ++ct)
            #pragma unroll
            for (int i = 0; i < 4; ++i)
                pmax = fmaxf(pmax, e[ct][i]);
        pmax = fmaxf(pmax, __shfl_xor(pmax, 16));
        pmax = fmaxf(pmax, __shfl_xor(pmax, 32));

        if (__any(pmax > m_r + 8.0f)) {
            const float mnew  = fmaxf(m_r, pmax);
            const float alpha = __builtin_amdgcn_exp2f(m_r - mnew);
            m_r = mnew;
            l_r *= alpha;
            float aO[4];
            #pragma unroll
            for (int i = 0; i < 4; ++i)
                aO[i] = __shfl(alpha, quad * 4 + i, 16);
            #pragma unroll
            for (int ct = 0; ct < 4; ++ct)
                #pragma unroll
                for (int i = 0; i < 4; ++i)
                    O[ct][i] *= aO[i];
        }

        float rs = 0.0f;
        #pragma unroll
        for (int ct = 0; ct < 4; ++ct) {
            bf16x4 pb;
            #pragma unroll
            for (int i = 0; i < 4; ++i) {
                const bf16 p = (bf16)__builtin_amdgcn_exp2f(e[ct][i] - m_r);
                pb[i] = p;
                rs += (float)p;
            }
            *(bf16x4*)&Ps[sidx(w * 16 + l15, ct * 16 + quad * 4)] = pb;
        }
        rs += __shfl_xor(rs, 16);
        rs += __shfl_xor(rs, 32);
        l_r += rs;

        #pragma unroll
        for (int ks = 0; ks < 64; ks += 32) {
            bf16x8 paf = *(const bf16x8*)&Ps[sidx(w * 16 + l15, ks + quad * 8)];
            #pragma unroll
            for (int ct = 0; ct < 4; ++ct) {
                bf16x8 vf = *(const bf16x8*)&Vts[cur][sidx(ct * 16 + l15, ks + quad * 8)];
                O[ct] = __builtin_amdgcn_mfma_f32_16x16x32_bf16(paf, vf, O[ct], 0, 0, 0);
            }
        }

        if (t + 1 < NT) {
            #pragma unroll
            for (int ct = 0; ct < 4; ++ct)
                md[ct] = mdn[ct];
        }
        __syncthreads();
    }

    float lO[4];
    #pragma unroll
    for (int i = 0; i < 4; ++i)
        lO[i] = 1.0f / __shfl(l_r, quad * 4 + i, 16);
    #pragma unroll
    for (int ct = 0; ct < 4; ++ct)
        #pragma unroll
        for (int i = 0; i < 4; ++i) {
            const int row = q0 + w * 16 + quad * 4 + i;
            const int col = h * HDn + ct * 16 + l15;
            att[((size_t)b * Sn + row) * Dn + col] = (bf16)(O[ct][i] * lO[i]);
        }
}

// ---------------------------------------------------------------------------
// Launch
// ---------------------------------------------------------------------------
extern "C" void kernel_launch(void* const* d_in, const int* in_sizes, int n_in,
                              void* d_out, int out_size, void* d_ws, size_t ws_size,
                              hipStream_t stream) {
    const float* x   = (const float*)d_in[0];
    const int*   kpm = (const int*)d_in[1];
    const float* mod = (const float*)d_in[2];
    const float* Wq  = (const float*)d_in[3];
    const float* bq  = (const float*)d_in[4];
    const float* Wk  = (const float*)d_in[5];
    const float* bk  = (const float*)d_in[6];
    const float* Wv  = (const float*)d_in[7];
    const float* bv  = (const float*)d_in[8];
    const float* Wo  = (const float*)d_in[9];
    const float* bo  = (const float*)d_in[10];
    float* out = (float*)d_out;

    // Workspace (bf16 unless noted): xb,qb,kb,vtb,attb (8.4M each) +
    // wqt|wkt|wvt|wot (1M each, contiguous -> wqt is Wqkv^T [3072][1024]) +
    // bqkv (3072 f32)
    bf16* ws = (bf16*)d_ws;
    const size_t sz = (size_t)Bn * Sn * Dn;   // 8388608
    const size_t wz = (size_t)Dn * Dn;        // 1048576
    bf16* xb   = ws;
    bf16* qb   = ws + sz;
    bf16* kb   = ws + 2 * sz;
    bf16* vtb  = ws + 3 * sz;
    bf16* attb = ws + 4 * sz;
    bf16* wqt  = ws + 5 * sz;
    bf16* wkt  = wqt + wz;
    bf16* wvt  = wkt + wz;
    bf16* wot  = wvt + wz;
    float* bqkv = (float*)(wot + wz);

    conv_f32_bf16_k<<<(int)(sz / 1024), 256, 0, stream>>>(x, xb, (int)sz);
    conv_wt_k<<<dim3(16, 16, 4), 256, 0, stream>>>(Wq, Wk, Wv, Wo, wqt, wkt, wvt, wot);
    bias_cat_k<<<12, 256, 0, stream>>>(bq, bk, bv, bqkv);

    // 0.125 (1/sqrt(hd)) * log2(e): folded into Q so attn runs in log2 domain
    const float SC = 0.125f * 1.44269504088896340736f;

    // Fused QKV: M=8192, N=3072, K=1024 -> grid 64x24
    gemm_qkv_k<<<dim3(64, 24), 256, 0, stream>>>(xb, wqt, bqkv, qb, kb, vtb, SC);

    attn_mfma_k<<<Bn * Hn * (Sn / 64), 256, 0, stream>>>(qb, kb, vtb, kpm, mod, attb);

    gemm_out_k<<<dim3(64, 8), 256, 0, stream>>>(attb, wot, bo, out);
}

// Round 9
// 416.182 us; speedup vs baseline: 1.0663x; 1.0109x over previous
//
#include <hip/hip_runtime.h>
#include <cstddef>

// Problem constants: B=4, S=2048, D=1024, H=16, HD=64
constexpr int Bn  = 4;
constexpr int Sn  = 2048;
constexpr int Dn  = 1024;
constexpr int Hn  = 16;
constexpr int HDn = 64;

typedef __bf16 bf16;
typedef __attribute__((ext_vector_type(8))) __bf16 bf16x8;
typedef __attribute__((ext_vector_type(4))) __bf16 bf16x4;
typedef __attribute__((ext_vector_type(4))) float  f32x4;

typedef __attribute__((address_space(1))) const void gvoid;
typedef __attribute__((address_space(3))) void lvoid;

// ---------------------------------------------------------------------------
// Elementwise fp32 -> bf16 (x staging)
// ---------------------------------------------------------------------------
__global__ __launch_bounds__(256) void conv_f32_bf16_k(
    const float* __restrict__ in, bf16* __restrict__ out, int n)
{
    int i = (blockIdx.x * 256 + threadIdx.x) * 4;
    if (i + 3 < n) {
        float4 v = *(const float4*)(in + i);
        bf16 o[4] = {(bf16)v.x, (bf16)v.y, (bf16)v.z, (bf16)v.w};
        *(ulong1*)(out + i) = *(ulong1*)o;  // 8B store
    }
}

// ---------------------------------------------------------------------------
// Bias concat: [bq|bk|bv] -> float[3072]
// ---------------------------------------------------------------------------
__global__ __launch_bounds__(256) void bias_cat_k(
    const float* __restrict__ bq, const float* __restrict__ bk,
    const float* __restrict__ bv, float* __restrict__ o)
{
    const int i = blockIdx.x * 256 + threadIdx.x;   // grid 12 -> 3072
    if (i < 1024)      o[i] = bq[i];
    else if (i < 2048) o[i] = bk[i - 1024];
    else if (i < 3072) o[i] = bv[i - 2048];
}

// ---------------------------------------------------------------------------
// Weight transpose + convert: W[k][n] fp32 -> Wt[n][k] bf16. 64x64 tiles.
// ---------------------------------------------------------------------------
__global__ __launch_bounds__(256) void conv_wt_k(
    const float* __restrict__ w0, const float* __restrict__ w1,
    const float* __restrict__ w2, const float* __restrict__ w3,
    bf16* __restrict__ o0, bf16* __restrict__ o1,
    bf16* __restrict__ o2, bf16* __restrict__ o3)
{
    const float* W = (blockIdx.z == 0) ? w0 : (blockIdx.z == 1) ? w1
                   : (blockIdx.z == 2) ? w2 : w3;
    bf16* O = (blockIdx.z == 0) ? o0 : (blockIdx.z == 1) ? o1
            : (blockIdx.z == 2) ? o2 : o3;
    __shared__ float t[64][65];
    const int tid = threadIdx.x;
    const int k0 = blockIdx.x * 64;   // row of W (k-dim)
    const int n0 = blockIdx.y * 64;   // col of W (n-dim)
    #pragma unroll
    for (int p = 0; p < 16; ++p) {
        const int idx = p * 256 + tid;
        const int r = idx >> 6, c = idx & 63;
        t[r][c] = W[(size_t)(k0 + r) * Dn + n0 + c];
    }
    __syncthreads();
    #pragma unroll
    for (int p = 0; p < 16; ++p) {
        const int idx = p * 256 + tid;
        const int r = idx >> 6, c = idx & 63;   // r: n-offset, c: k-offset
        O[(size_t)(n0 + r) * Dn + k0 + c] = (bf16)t[c][r];
    }
}

// ---------------------------------------------------------------------------
// 2-PHASE GEMM with COUNTED vmcnt (T4, m218: counted-vs-drain0 = +38..73%).
// R8 post-mortem: __syncthreads drains vmcnt(0) at the barrier, killing the
// prefetch (only +7%). Fix: raw s_barrier + asm s_waitcnt vmcnt(8) — the 8
// newest loads (next tile's stage) stay in flight across the barrier; only
// the last tile waits vmcnt(0). sched_barrier(0) pins LDS ops from crossing
// the fence-less raw barriers (rule-18 analog).
// Per-iter: { stage(t+1); vmcnt(8); s_barrier; compute(t); s_barrier; }
// ---------------------------------------------------------------------------
#define GEMM_STAGE(Ap, Bp, k0, boff)                                          \
    {                                                                         \
        _Pragma("unroll")                                                     \
        for (int j = 0; j < 4; ++j) {                                         \
            const int rbase = (w * 4 + j) * 8;                                \
            const int r = rbase + srow;                                       \
            __builtin_amdgcn_global_load_lds(                                 \
                (gvoid*)(Ap + (size_t)(m0 + r) * Dn + (k0) + scol),           \
                (lvoid*)&smem[(boff) + rbase * 64], 16, 0, 0);                \
            __builtin_amdgcn_global_load_lds(                                 \
                (gvoid*)(Bp + (size_t)(n0 + r) * Dn + (k0) + scol),           \
                (lvoid*)&smem[(boff) + 128 * 64 + rbase * 64], 16, 0, 0);     \
        }                                                                     \
    }

#define GEMM_COMPUTE(boff)                                                    \
    {                                                                         \
        _Pragma("unroll")                                                     \
        for (int ks = 0; ks < 64; ks += 32) {                                 \
            bf16x8 af[4], bfr[4];                                             \
            _Pragma("unroll")                                                 \
            for (int fm = 0; fm < 4; ++fm)                                    \
                af[fm] = *(const bf16x8*)&smem[(boff) +                       \
                    (wm * 64 + fm * 16 + l15) * 64 + ks + quad * 8];          \
            _Pragma("unroll")                                                 \
            for (int fn = 0; fn < 4; ++fn)                                    \
                bfr[fn] = *(const bf16x8*)&smem[(boff) + 128 * 64 +           \
                    (wn * 64 + fn * 16 + l15) * 64 + ks + quad * 8];          \
            _Pragma("unroll")                                                 \
            for (int fm = 0; fm < 4; ++fm)                                    \
                _Pragma("unroll")                                             \
                for (int fn = 0; fn < 4; ++fn)                                \
                    acc[fm][fn] = __builtin_amdgcn_mfma_f32_16x16x32_bf16(    \
                        af[fm], bfr[fn], acc[fm][fn], 0, 0, 0);               \
        }                                                                     \
    }

// Counted-vmcnt pipelined K-loop (shared by both GEMMs)
#define GEMM_KLOOP(Ap, Bp)                                                    \
    GEMM_STAGE(Ap, Bp, 0, 0);                                                 \
    int boff = 0;                                                             \
    for (int kt = 0; kt < Dn / 64; ++kt) {                                    \
        if (kt + 1 < Dn / 64) {                                               \
            GEMM_STAGE(Ap, Bp, (kt + 1) * 64, boff ^ BUF);                    \
            asm volatile("s_waitcnt vmcnt(8)" ::: "memory");                  \
        } else {                                                              \
            asm volatile("s_waitcnt vmcnt(0)" ::: "memory");                  \
        }                                                                     \
        __builtin_amdgcn_s_barrier();                                         \
        __builtin_amdgcn_sched_barrier(0);                                    \
        GEMM_COMPUTE(boff);                                                   \
        __builtin_amdgcn_sched_barrier(0);                                    \
        __builtin_amdgcn_s_barrier();                                         \
        boff ^= BUF;                                                          \
    }

constexpr int BUF = 2 * 128 * 64;   // elements per (A,B) buffer pair

// ---------------------------------------------------------------------------
// Final-projection GEMM: out_f32 = A(8192x1024) @ Bt^T + bias.
// ---------------------------------------------------------------------------
__global__ __launch_bounds__(256) void gemm_out_k(
    const bf16* __restrict__ A, const bf16* __restrict__ Bt,
    const float* __restrict__ bias, float* __restrict__ outv)
{
    __shared__ __align__(16) bf16 smem[2 * BUF];

    const int tid  = threadIdx.x;
    const int w    = tid >> 6;
    const int lane = tid & 63;
    const int quad = lane >> 4;
    const int l15  = lane & 15;
    const int m0   = blockIdx.x * 128;
    const int n0   = blockIdx.y * 128;
    const int wm   = w >> 1;
    const int wn   = w & 1;
    const int srow = lane >> 3;
    const int scol = (lane & 7) * 8;

    f32x4 acc[4][4] = {};

    GEMM_KLOOP(A, Bt);

    #pragma unroll
    for (int fn = 0; fn < 4; ++fn) {
        const int c = n0 + wn * 64 + fn * 16 + l15;
        const float bv = bias[c];
        #pragma unroll
        for (int fm = 0; fm < 4; ++fm)
            #pragma unroll
            for (int i = 0; i < 4; ++i) {
                const int m = m0 + wm * 64 + fm * 16 + quad * 4 + i;
                outv[(size_t)m * Dn + c] = acc[fm][fn][i] + bv;
            }
    }
}

// ---------------------------------------------------------------------------
// FUSED QKV GEMM: A(8192x1024) @ Wqkv^T(3072x1024) + bias_cat, grid 64x24.
// Epilogue block-uniform on section = n0>>10:
//   sec 0 (Q): bf16 [b,h,s,hd] scaled by scq; sec 1 (K): bf16 [b,h,s,hd];
//   sec 2 (V): bf16 [b,h,hd,s] via LDS-transposed coalesced store.
// ---------------------------------------------------------------------------
__global__ __launch_bounds__(256) void gemm_qkv_k(
    const bf16* __restrict__ A, const bf16* __restrict__ Wt,
    const float* __restrict__ bias, bf16* __restrict__ qout,
    bf16* __restrict__ kout, bf16* __restrict__ vout, float scq)
{
    __shared__ __align__(16) bf16 smem[2 * BUF];   // 64KB; V-transpose reuses

    const int tid  = threadIdx.x;
    const int w    = tid >> 6;
    const int lane = tid & 63;
    const int quad = lane >> 4;
    const int l15  = lane & 15;
    const int m0   = blockIdx.x * 128;
    const int n0   = blockIdx.y * 128;   // in [0, 3072)
    const int wm   = w >> 1;
    const int wn   = w & 1;
    const int srow = lane >> 3;
    const int scol = (lane & 7) * 8;

    f32x4 acc[4][4] = {};

    GEMM_KLOOP(A, Wt);

    const int sec = n0 >> 10;            // 0=Q, 1=K, 2=V (block-uniform)
    const int cb  = n0 & 1023;           // column base within the section

    if (sec < 2) {
        bf16* const outp = sec ? kout : qout;
        const float scale = sec ? 1.0f : scq;
        #pragma unroll
        for (int fn = 0; fn < 4; ++fn) {
            const int cc = cb + wn * 64 + fn * 16 + l15;
            const float bv = bias[n0 + wn * 64 + fn * 16 + l15];
            const int h = cc >> 6, hd = cc & 63;
            #pragma unroll
            for (int fm = 0; fm < 4; ++fm)
                #pragma unroll
                for (int i = 0; i < 4; ++i) {
                    const int m = m0 + wm * 64 + fm * 16 + quad * 4 + i;
                    const int b = m >> 11, s = m & (Sn - 1);
                    outp[(((size_t)(b * Hn + h) * Sn) + s) * HDn + hd] =
                        (bf16)((acc[fm][fn][i] + bv) * scale);
                }
        }
    } else {
        // V: transpose through LDS (pad 136), then coalesced 256B row stores.
        bf16* const T = smem;    // reuse after final barrier of the main loop
        #pragma unroll
        for (int fn = 0; fn < 4; ++fn) {
            const int n = wn * 64 + fn * 16 + l15;
            const float bv = bias[n0 + n];
            #pragma unroll
            for (int fm = 0; fm < 4; ++fm) {
                const int m = wm * 64 + fm * 16 + quad * 4;
                bf16x4 pk;
                #pragma unroll
                for (int i = 0; i < 4; ++i)
                    pk[i] = (bf16)(acc[fm][fn][i] + bv);
                *(bf16x4*)&T[n * 136 + m] = pk;
            }
        }
        __syncthreads();
        const int b  = m0 >> 11;
        const int s0 = m0 & (Sn - 1);
        #pragma unroll
        for (int it = 0; it < 8; ++it) {
            const int n    = it * 16 + (tid >> 4);       // 0..127
            const int mcol = (tid & 15) * 8;
            const int gh = (cb + n) >> 6, ghd = (cb + n) & 63;
            bf16x8 v = *(const bf16x8*)&T[n * 136 + mcol];
            *(bf16x8*)(vout +
                (((size_t)(b * Hn + gh) * HDn) + ghd) * Sn + s0 + mcol) = v;
        }
    }
}

// ---------------------------------------------------------------------------
// LDS XOR-swizzle (element-index form): 16B chunk column ^= row&7.
// ---------------------------------------------------------------------------
__device__ __forceinline__ int sidx(int r, int c) {
    return r * 64 + (c ^ ((r & 7) << 3));
}

// ---------------------------------------------------------------------------
// Flash attention, QBLK=128 @ 512 threads (8 waves x 16 q-rows):
//  - same 64-key K/Vt staging now amortized over 2x q-rows; 1 DMA pair/thread
//  - LDS 48KB -> 3 blocks/CU (24 waves potential vs 16)   [launch_bounds 512,6]
//  - VALU diet: query-mask folded into FMA (qbias=-1e30: |s*md| << ulp(1e30)
//    so masked rows are EXACTLY -1e30 -> uniform softmax, matches reference);
//    tree-shaped pmax/rs reductions (dep chains 15 -> 4)
//  - otherwise the frozen R4-R8 structure: swapped QK^T, log2-domain softmax,
//    DMA-staged double-buffered K/Vt (pre-swizzled source), defer-max.
// ---------------------------------------------------------------------------
__global__ __launch_bounds__(512, 6) void attn_mfma_k(
    const bf16* __restrict__ Qb, const bf16* __restrict__ Kb,
    const bf16* __restrict__ Vtb, const int* __restrict__ kpm,
    const float* __restrict__ mod, bf16* __restrict__ att)
{
    __shared__ __align__(16) bf16 Ks[2][64 * 64];
    __shared__ __align__(16) bf16 Vts[2][64 * 64];
    __shared__ __align__(16) bf16 Ps[128 * 64];

    const int tid  = threadIdx.x;
    const int w    = tid >> 6;             // 0..7
    const int lane = tid & 63;
    const int quad = lane >> 4;
    const int l15  = lane & 15;
    const int blk  = blockIdx.x;
    const int bh   = blk >> 4;             // q-tile innermost: K/V L2-reuse
    const int q0   = (blk & 15) * 128;
    const int b    = bh >> 4;
    const int h    = bh & 15;
    const size_t base = (size_t)bh * Sn * HDn;

    const int qrow = q0 + w * 16 + l15;    // this lane's softmax q-row
    const bf16x8 qf0 = *(const bf16x8*)(Qb + base + (size_t)qrow * HDn + 0  + quad * 8);
    const bf16x8 qf1 = *(const bf16x8*)(Qb + base + (size_t)qrow * HDn + 32 + quad * 8);

    // Query-mask as additive bias: -1e30 + s*md == -1e30 exactly (|s*md| <<
    // ulp(1e30)) -> masked rows get uniform softmax, matching the reference.
    const float qbias = (kpm[(size_t)b * Sn + qrow] != 0) ? -1e30f : 0.0f;
    const float* modrow = mod + ((size_t)b * Sn + qrow) * Sn;

    float m_r = -1e30f;
    float l_r = 0.0f;
    f32x4 O[4] = {};

    // DMA staging: wave w covers rows w*8..w*8+7 of both 64-row tiles.
    // Source col pre-swizzled so the linear DMA write lands XOR-swizzled.
    const int rl = lane >> 3;                       // 0..7
    const int cg = ((lane & 7) ^ rl) * 8;           // swizzled source elems
    const int gb = w * 8;                           // group base row

    auto stage = [&](int t, int buf) {
        const int k0 = t * 64;
        __builtin_amdgcn_global_load_lds(
            (gvoid*)(Kb + base + (size_t)(k0 + gb + rl) * HDn + cg),
            (lvoid*)&Ks[buf][gb * 64], 16, 0, 0);
        __builtin_amdgcn_global_load_lds(
            (gvoid*)(Vtb + base + (size_t)(gb + rl) * Sn + k0 + cg),
            (lvoid*)&Vts[buf][gb * 64], 16, 0, 0);
    };

    stage(0, 0);
    float4 md[4];
    #pragma unroll
    for (int ct = 0; ct < 4; ++ct)
        md[ct] = *(const float4*)(modrow + ct * 16 + quad * 4);
    __syncthreads();

    constexpr int NT = Sn / 64;
    for (int t = 0; t < NT; ++t) {
        const int cur = t & 1;

        float4 mdn[4];
        if (t + 1 < NT) {
            stage(t + 1, cur ^ 1);
            #pragma unroll
            for (int ct = 0; ct < 4; ++ct)
                mdn[ct] = *(const float4*)(modrow + (t + 1) * 64 + ct * 16 + quad * 4);
        }

        // QK^T (swapped): lane holds e[k = ct*16+quad*4+i] for its q-row
        float e[4][4];
        #pragma unroll
        for (int ct = 0; ct < 4; ++ct) {
            f32x4 s = {};
            #pragma unroll
            for (int ks = 0; ks < 64; ks += 32) {
                bf16x8 kf = *(const bf16x8*)&Ks[cur][sidx(ct * 16 + l15, ks + quad * 8)];
                s = __builtin_amdgcn_mfma_f32_16x16x32_bf16(kf, ks ? qf1 : qf0, s, 0, 0, 0);
            }
            #pragma unroll
            for (int i = 0; i < 4; ++i)
                e[ct][i] = fmaf(s[i], (&md[ct].x)[i], qbias);
        }

        // row max: tree (depth 4) + 2 cross-quad shfl
        float pm[4];
        #pragma unroll
        for (int ct = 0; ct < 4; ++ct)
            pm[ct] = fmaxf(fmaxf(e[ct][0], e[ct][1]), fmaxf(e[ct][2], e[ct][3]));
        float pmax = fmaxf(fmaxf(pm[0], pm[1]), fmaxf(pm[2], pm[3]));
        pmax = fmaxf(pmax, __shfl_xor(pmax, 16));
        pmax = fmaxf(pmax, __shfl_xor(pmax, 32));

        // T13 defer-max: only rescale when some row's max grew past THR=8
        if (__any(pmax > m_r + 8.0f)) {
            const float mnew  = fmaxf(m_r, pmax);
            const float alpha = __builtin_amdgcn_exp2f(m_r - mnew);
            m_r = mnew;
            l_r *= alpha;
            float aO[4];
            #pragma unroll
            for (int i = 0; i < 4; ++i)
                aO[i] = __shfl(alpha, quad * 4 + i, 16);
            #pragma unroll
            for (int ct = 0; ct < 4; ++ct)
                #pragma unroll
                for (int i = 0; i < 4; ++i)
                    O[ct][i] *= aO[i];
        }

        // P = exp2(e - m), bf16-rounded; [q][k] via ds_write_b64 (swizzled);
        // rs as tree of rounded values (numerator-consistent denominator)
        float rsc[4];
        #pragma unroll
        for (int ct = 0; ct < 4; ++ct) {
            bf16x4 pb;
            float pf[4];
            #pragma unroll
            for (int i = 0; i < 4; ++i) {
                const bf16 p = (bf16)__builtin_amdgcn_exp2f(e[ct][i] - m_r);
                pb[i] = p;
                pf[i] = (float)p;
            }
            rsc[ct] = (pf[0] + pf[1]) + (pf[2] + pf[3]);
            *(bf16x4*)&Ps[sidx(w * 16 + l15, ct * 16 + quad * 4)] = pb;
        }
        float rs = (rsc[0] + rsc[1]) + (rsc[2] + rsc[3]);
        rs += __shfl_xor(rs, 16);
        rs += __shfl_xor(rs, 32);
        l_r += rs;

        // O += P V (Ps rows are wave-local; same-wave RAW via lgkmcnt)
        #pragma unroll
        for (int ks = 0; ks < 64; ks += 32) {
            bf16x8 paf = *(const bf16x8*)&Ps[sidx(w * 16 + l15, ks + quad * 8)];
            #pragma unroll
            for (int ct = 0; ct < 4; ++ct) {
                bf16x8 vf = *(const bf16x8*)&Vts[cur][sidx(ct * 16 + l15, ks + quad * 8)];
                O[ct] = __builtin_amdgcn_mfma_f32_16x16x32_bf16(paf, vf, O[ct], 0, 0, 0);
            }
        }

        if (t + 1 < NT) {
            #pragma unroll
            for (int ct = 0; ct < 4; ++ct)
                md[ct] = mdn[ct];
        }
        // ONE barrier: (a) all reads of buf cur done before t+1 overwrites it
        // next iter; (b) implicit vmcnt(0) drain => chunk t+1 DMA landed.
        __syncthreads();
    }

    float lO[4];
    #pragma unroll
    for (int i = 0; i < 4; ++i)
        lO[i] = 1.0f / __shfl(l_r, quad * 4 + i, 16);
    #pragma unroll
    for (int ct = 0; ct < 4; ++ct)
        #pragma unroll
        for (int i = 0; i < 4; ++i) {
            const int row = q0 + w * 16 + quad * 4 + i;
            const int col = h * HDn + ct * 16 + l15;
            att[((size_t)b * Sn + row) * Dn + col] = (bf16)(O[ct][i] * lO[i]);
        }
}

// ---------------------------------------------------------------------------
// Launch
// ---------------------------------------------------------------------------
extern "C" void kernel_launch(void* const* d_in, const int* in_sizes, int n_in,
                              void* d_out, int out_size, void* d_ws, size_t ws_size,
                              hipStream_t stream) {
    const float* x   = (const float*)d_in[0];
    const int*   kpm = (const int*)d_in[1];
    const float* mod = (const float*)d_in[2];
    const float* Wq  = (const float*)d_in[3];
    const float* bq  = (const float*)d_in[4];
    const float* Wk  = (const float*)d_in[5];
    const float* bk  = (const float*)d_in[6];
    const float* Wv  = (const float*)d_in[7];
    const float* bv  = (const float*)d_in[8];
    const float* Wo  = (const float*)d_in[9];
    const float* bo  = (const float*)d_in[10];
    float* out = (float*)d_out;

    // Workspace (bf16 unless noted): xb,qb,kb,vtb,attb (8.4M each) +
    // wqt|wkt|wvt|wot (1M each, contiguous -> wqt is Wqkv^T [3072][1024]) +
    // bqkv (3072 f32)
    bf16* ws = (bf16*)d_ws;
    const size_t sz = (size_t)Bn * Sn * Dn;   // 8388608
    const size_t wz = (size_t)Dn * Dn;        // 1048576
    bf16* xb   = ws;
    bf16* qb   = ws + sz;
    bf16* kb   = ws + 2 * sz;
    bf16* vtb  = ws + 3 * sz;
    bf16* attb = ws + 4 * sz;
    bf16* wqt  = ws + 5 * sz;
    bf16* wkt  = wqt + wz;
    bf16* wvt  = wkt + wz;
    bf16* wot  = wvt + wz;
    float* bqkv = (float*)(wot + wz);

    conv_f32_bf16_k<<<(int)(sz / 1024), 256, 0, stream>>>(x, xb, (int)sz);
    conv_wt_k<<<dim3(16, 16, 4), 256, 0, stream>>>(Wq, Wk, Wv, Wo, wqt, wkt, wvt, wot);
    bias_cat_k<<<12, 256, 0, stream>>>(bq, bk, bv, bqkv);

    // 0.125 (1/sqrt(hd)) * log2(e): folded into Q so attn runs in log2 domain
    const float SC = 0.125f * 1.44269504088896340736f;

    // Fused QKV: M=8192, N=3072, K=1024 -> grid 64x24
    gemm_qkv_k<<<dim3(64, 24), 256, 0, stream>>>(xb, wqt, bqkv, qb, kb, vtb, SC);

    attn_mfma_k<<<Bn * Hn * (Sn / 128), 512, 0, stream>>>(qb, kb, vtb, kpm, mod, attb);

    gemm_out_k<<<dim3(64, 8), 256, 0, stream>>>(attb, wot, bo, out);
}